// Round 1
// baseline (849.590 us; speedup 1.0000x reference)
//
#include <hip/hip_runtime.h>
#include <math.h>

#define B_ 2
#define N_ 2048
#define DIM_ 512
#define H_ 8
#define D_ 64
#define M_ 128
#define INNER_ 512
#define NC_ 32
#define C_ 64

#define INV_SQRT_M 0.08838834764831845f
#define QK_SCALE 0.35355339059327373f

// ---------------- QKV projection: y = x @ W^T, scaled, written [B,H,N,D] ----------------
__global__ __launch_bounds__(256) void qkv_gemm(const float* __restrict__ x,
    const float* __restrict__ Wq, const float* __restrict__ Wk, const float* __restrict__ Wv,
    float* __restrict__ q, float* __restrict__ k, float* __restrict__ v)
{
    const int which = blockIdx.z;
    const float* W = (which == 0) ? Wq : ((which == 1) ? Wk : Wv);
    float* out = (which == 0) ? q : ((which == 1) ? k : v);
    const float sc = (which == 2) ? 1.0f : QK_SCALE;
    __shared__ float As[32][33];
    __shared__ float Bs[32][33];
    const int tx = threadIdx.x & 31, ty = threadIdx.x >> 5;
    const int row0 = blockIdx.x * 32, col0 = blockIdx.y * 32;
    float acc[4] = {0.f, 0.f, 0.f, 0.f};
    for (int k0 = 0; k0 < DIM_; k0 += 32) {
        #pragma unroll
        for (int r = 0; r < 4; ++r) {
            As[ty + 8*r][tx] = x[(size_t)(row0 + ty + 8*r) * DIM_ + k0 + tx];
            Bs[ty + 8*r][tx] = W[(size_t)(col0 + ty + 8*r) * DIM_ + k0 + tx];
        }
        __syncthreads();
        #pragma unroll
        for (int kk = 0; kk < 32; ++kk) {
            float bv = Bs[tx][kk];
            #pragma unroll
            for (int r = 0; r < 4; ++r) acc[r] += As[ty + 8*r][kk] * bv;
        }
        __syncthreads();
    }
    const int j = col0 + tx;
    const int h = j >> 6, d = j & 63;
    #pragma unroll
    for (int r = 0; r < 4; ++r) {
        int i = row0 + ty + 8*r;
        int b = i >> 11, n = i & 2047;
        out[(((size_t)(b * H_ + h)) * N_ + n) * D_ + d] = acc[r] * sc;
    }
}

// ---------------- phi: per (b,h,n) row -> M features ----------------
__global__ __launch_bounds__(128) void phi_kernel(const float* __restrict__ qk,
    const float* __restrict__ omega, float* __restrict__ outp, float* __restrict__ partmax,
    int is_query)
{
    const int bid = blockIdx.x;   // (b*H+h)*N + n
    const int t = threadIdx.x;    // m in [0,128)
    __shared__ float qs[D_];
    __shared__ float wred[2];
    if (t < D_) qs[t] = qk[(size_t)bid * D_ + t];
    __syncthreads();
    float ss = 0.f;
    #pragma unroll
    for (int d2 = 0; d2 < D_; ++d2) ss += qs[d2] * qs[d2];
    float proj = 0.f;
    const float* om = omega + (size_t)t * D_;
    #pragma unroll 8
    for (int d2 = 0; d2 < D_; ++d2) proj += qs[d2] * om[d2];
    float lp = proj - 0.5f * ss;
    float mx = lp;
    #pragma unroll
    for (int off = 1; off < 64; off <<= 1) mx = fmaxf(mx, __shfl_xor(mx, off));
    if ((t & 63) == 0) wred[t >> 6] = mx;
    __syncthreads();
    float bm = fmaxf(wred[0], wred[1]);
    if (is_query) {
        outp[(size_t)bid * M_ + t] = expf(lp - bm) * INV_SQRT_M + 1e-4f;
    } else {
        outp[(size_t)bid * M_ + t] = lp;  // store log-phi, exp later after global max
        if (t == 0) partmax[bid] = bm;
    }
}

__global__ void gmax_kernel(const float* __restrict__ partmax, float* __restrict__ gmax)
{
    float m = -3.402823466e38f;
    for (int i = threadIdx.x; i < B_ * H_ * N_; i += 256) m = fmaxf(m, partmax[i]);
    #pragma unroll
    for (int off = 1; off < 64; off <<= 1) m = fmaxf(m, __shfl_xor(m, off));
    __shared__ float w[4];
    if ((threadIdx.x & 63) == 0) w[threadIdx.x >> 6] = m;
    __syncthreads();
    if (threadIdx.x == 0) gmax[0] = fmaxf(fmaxf(w[0], w[1]), fmaxf(w[2], w[3]));
}

__global__ void phik_exp(float* __restrict__ phi_k, const float* __restrict__ gmax)
{
    const float g = gmax[0];
    int i = blockIdx.x * blockDim.x + threadIdx.x;
    const int stride = gridDim.x * blockDim.x;
    for (; i < B_ * H_ * N_ * M_; i += stride)
        phi_k[i] = expf(phi_k[i] - g) * INV_SQRT_M + 1e-4f;
}

// ---------------- per-chunk KV sums: S_j[m][d] = sum_n pk[n][m] v[n][d] ----------------
__global__ __launch_bounds__(256) void chunk_kv(const float* __restrict__ phi_k,
    const float* __restrict__ v, float* __restrict__ S, float* __restrict__ ksum)
{
    __shared__ float pk[C_][129];
    __shared__ float vs[C_][65];
    const int t = threadIdx.x;
    const int bh = blockIdx.x / NC_, j = blockIdx.x % NC_;
    const int n0 = j * C_;
    for (int idx = t; idx < C_ * M_; idx += 256) {
        int r = idx >> 7, c = idx & 127;
        pk[r][c] = phi_k[((size_t)(bh * N_ + n0 + r)) * M_ + c];
    }
    for (int idx = t; idx < C_ * D_; idx += 256) {
        int r = idx >> 6, c = idx & 63;
        vs[r][c] = v[((size_t)(bh * N_ + n0 + r)) * D_ + c];
    }
    __syncthreads();
    const int d = t & 63;
    const int m0 = (t >> 6) * 32;
    float acc[32];
    #pragma unroll
    for (int mm = 0; mm < 32; ++mm) acc[mm] = 0.f;
    for (int n = 0; n < C_; ++n) {
        float vv = vs[n][d];
        #pragma unroll
        for (int mm = 0; mm < 32; ++mm) acc[mm] += pk[n][m0 + mm] * vv;
    }
    size_t sbase = ((size_t)(bh * NC_ + j)) * M_ * D_;
    for (int mm = 0; mm < 32; ++mm)
        S[sbase + (size_t)(m0 + mm) * D_ + d] = acc[mm];
    if (t < M_) {
        float s = 0.f;
        for (int n = 0; n < C_; ++n) s += pk[n][t];
        ksum[((size_t)(bh * NC_ + j)) * M_ + t] = s;
    }
}

// ---------------- exclusive prefix over chunks (in place) ----------------
__global__ __launch_bounds__(256) void prefix_kernel(float* __restrict__ S, float* __restrict__ ksum)
{
    const int bh = blockIdx.x;
    const int t = threadIdx.x;
    for (int e = t; e < M_ * D_; e += 256) {
        float run = 0.f;
        for (int j = 0; j < NC_; ++j) {
            float* p = S + ((size_t)(bh * NC_ + j)) * M_ * D_ + e;
            float val = *p; *p = run; run += val;
        }
    }
    if (t < M_) {
        float run = 0.f;
        for (int j = 0; j < NC_; ++j) {
            float* p = ksum + ((size_t)(bh * NC_ + j)) * M_ + t;
            float val = *p; *p = run; run += val;
        }
    }
}

// ---------------- per-chunk output ----------------
__global__ __launch_bounds__(256) void chunk_out(const float* __restrict__ phi_q,
    const float* __restrict__ phi_k, const float* __restrict__ v,
    const float* __restrict__ S, const float* __restrict__ ksum,
    float* __restrict__ o)
{
    __shared__ float pq[C_][129];
    __shared__ float pkSp[M_ * 65];   // first pk [64][129], later Sp [128][65]
    __shared__ float vs[C_][65];
    __shared__ float As[C_][65];
    __shared__ float ksp[M_];
    __shared__ float den[C_];
    const int t = threadIdx.x;
    const int bh = blockIdx.x / NC_, j = blockIdx.x % NC_;
    const int n0 = j * C_;
    for (int idx = t; idx < C_ * M_; idx += 256) {
        int r = idx >> 7, c = idx & 127;
        size_t g = ((size_t)(bh * N_ + n0 + r)) * M_ + c;
        pq[r][c] = phi_q[g];
        pkSp[r * 129 + c] = phi_k[g];
    }
    for (int idx = t; idx < C_ * D_; idx += 256) {
        int r = idx >> 6, c = idx & 63;
        vs[r][c] = v[((size_t)(bh * N_ + n0 + r)) * D_ + c];
    }
    __syncthreads();
    // A = pq @ pk^T with causal (inclusive) mask
    {
        const int i = t >> 2;
        const int jq = (t & 3) * 16;
        for (int jj = 0; jj < 16; ++jj) {
            int jcol = jq + jj;
            float a = 0.f;
            if (jcol <= i) {
                for (int m = 0; m < M_; ++m) a += pq[i][m] * pkSp[jcol * 129 + m];
            }
            As[i][jcol] = a;
        }
    }
    __syncthreads();
    // overwrite pk region with S prefix [M][D] (stride 65); load ksum prefix
    for (int idx = t; idx < M_ * D_; idx += 256) {
        int r = idx >> 6, c = idx & 63;
        pkSp[r * 65 + c] = S[((size_t)(bh * NC_ + j)) * M_ * D_ + idx];
    }
    if (t < M_) ksp[t] = ksum[((size_t)(bh * NC_ + j)) * M_ + t];
    __syncthreads();
    // denominators
    if (t < C_) {
        float rs = 0.f;
        for (int jc = 0; jc < C_; ++jc) rs += As[t][jc];
        for (int m = 0; m < M_; ++m) rs += pq[t][m] * ksp[m];
        den[t] = 1.0f / (rs + 1e-6f);
    }
    __syncthreads();
    // outputs
    const int d = t & 63;
    const int i0 = (t >> 6) * 16;
    for (int ii = 0; ii < 16; ++ii) {
        int i = i0 + ii;
        float acc = 0.f;
        for (int jc = 0; jc < C_; ++jc) acc += As[i][jc] * vs[jc][d];
        for (int m = 0; m < M_; ++m) acc += pq[i][m] * pkSp[m * 65 + d];
        o[((size_t)(bh * N_ + n0 + i)) * D_ + d] = acc * den[i];
    }
}

// ---------------- output projection: out = o_concat @ Wo^T + bo ----------------
__global__ __launch_bounds__(256) void out_gemm(const float* __restrict__ o,
    const float* __restrict__ Wo, const float* __restrict__ bo, float* __restrict__ outp)
{
    __shared__ float As[32][33];
    __shared__ float Bs[32][33];
    const int tx = threadIdx.x & 31, ty = threadIdx.x >> 5;
    const int row0 = blockIdx.x * 32, col0 = blockIdx.y * 32;
    float acc[4] = {0.f, 0.f, 0.f, 0.f};
    for (int k0 = 0; k0 < INNER_; k0 += 32) {
        #pragma unroll
        for (int r = 0; r < 4; ++r) {
            int i = row0 + ty + 8*r;
            int kcol = k0 + tx;
            int b = i >> 11, n = i & 2047;
            int h = kcol >> 6, d = kcol & 63;
            As[ty + 8*r][tx] = o[(((size_t)(b * H_ + h)) * N_ + n) * D_ + d];
            Bs[ty + 8*r][tx] = Wo[(size_t)(col0 + ty + 8*r) * INNER_ + k0 + tx];
        }
        __syncthreads();
        #pragma unroll
        for (int kk = 0; kk < 32; ++kk) {
            float bv = Bs[tx][kk];
            #pragma unroll
            for (int r = 0; r < 4; ++r) acc[r] += As[ty + 8*r][kk] * bv;
        }
        __syncthreads();
    }
    const int jcol = col0 + tx;
    const float bias = bo[jcol];
    #pragma unroll
    for (int r = 0; r < 4; ++r) {
        int i = row0 + ty + 8*r;
        outp[(size_t)i * DIM_ + jcol] = acc[r] + bias;
    }
}

extern "C" void kernel_launch(void* const* d_in, const int* in_sizes, int n_in,
                              void* d_out, int out_size, void* d_ws, size_t ws_size,
                              hipStream_t stream) {
    const float* x     = (const float*)d_in[0];
    const float* omega = (const float*)d_in[1];
    const float* Wq    = (const float*)d_in[2];
    const float* Wk    = (const float*)d_in[3];
    const float* Wv    = (const float*)d_in[4];
    const float* Wo    = (const float*)d_in[5];
    const float* bo    = (const float*)d_in[6];
    float* out = (float*)d_out;

    const size_t QS = (size_t)B_ * H_ * N_ * D_;   // 2,097,152
    const size_t PS = (size_t)B_ * H_ * N_ * M_;   // 4,194,304
    const size_t SS = (size_t)B_ * H_ * NC_ * M_ * D_;  // 4,194,304
    const size_t KS = (size_t)B_ * H_ * NC_ * M_;  // 65,536
    const size_t PM = (size_t)B_ * H_ * N_;        // 32,768

    float* ws = (float*)d_ws;
    float* q      = ws;                 // reused later as attention output o
    float* k      = q + QS;
    float* v      = k + QS;
    float* phi_q  = v + QS;
    float* phi_k  = phi_q + PS;
    float* S      = phi_k + PS;
    float* ksum   = S + SS;
    float* partmax= ksum + KS;
    float* gmax   = partmax + PM;

    // 1. QKV projections
    qkv_gemm<<<dim3(B_ * N_ / 32, INNER_ / 32, 3), 256, 0, stream>>>(x, Wq, Wk, Wv, q, k, v);

    // 2. phi features
    phi_kernel<<<B_ * H_ * N_, 128, 0, stream>>>(q, omega, phi_q, nullptr, 1);
    phi_kernel<<<B_ * H_ * N_, 128, 0, stream>>>(k, omega, phi_k, partmax, 0);
    gmax_kernel<<<1, 256, 0, stream>>>(partmax, gmax);
    phik_exp<<<2048, 256, 0, stream>>>(phi_k, gmax);

    // 3. chunked causal linear attention
    chunk_kv<<<B_ * H_ * NC_, 256, 0, stream>>>(phi_k, v, S, ksum);
    prefix_kernel<<<B_ * H_, 256, 0, stream>>>(S, ksum);
    chunk_out<<<B_ * H_ * NC_, 256, 0, stream>>>(phi_q, phi_k, v, S, ksum, q /* o reuses q */);

    // 4. output projection
    out_gemm<<<dim3(B_ * N_ / 32, DIM_ / 32), 256, 0, stream>>>(q, Wo, bo, out);
}

// Round 2
// 255.091 us; speedup vs baseline: 3.3305x; 3.3305x over previous
//
#include <hip/hip_runtime.h>
#include <math.h>

#define B_ 2
#define N_ 2048
#define DIM_ 512
#define H_ 8
#define D_ 64
#define M_ 128
#define NC_ 32
#define C_ 64

#define INV_SQRT_M 0.08838834764831845f
#define QK_SCALE 0.35355339059327373f

typedef __attribute__((ext_vector_type(8))) short bf16x8;
typedef __attribute__((ext_vector_type(4))) short bf16x4;
typedef __attribute__((ext_vector_type(4))) float f32x4;

#define MFMA16(a, b, c) __builtin_amdgcn_mfma_f32_16x16x32_bf16((a), (b), (c), 0, 0, 0)

__device__ __forceinline__ short f2bf(float f) {
    union { float f; unsigned u; } x; x.f = f;
    unsigned r = (x.u + 0x7FFFu + ((x.u >> 16) & 1u)) >> 16;
    return (short)r;
}
__device__ __forceinline__ float bf2f(short s) {
    union { unsigned u; float f; } x; x.u = ((unsigned)(unsigned short)s) << 16;
    return x.f;
}

// fragment load from row-major LDS tile [rows][ldk] bf16 (B^T / A form):
// elem i = T[row0 + (lane&15)][k0 + (lane>>4)*8 + i]   (contiguous 16B)
__device__ __forceinline__ bf16x8 ld_frag(const short* base, int row0, int k0, int ldk) {
    const int lane = threadIdx.x & 63;
    return *(const bf16x8*)(base + (row0 + (lane & 15)) * ldk + k0 + ((lane >> 4) << 3));
}
// strided (transposed) fragment load: operand stored [K][cols] row-major:
// elem i = T[k0 + (lane>>4)*8 + i][col0 + (lane&15)]
__device__ __forceinline__ bf16x8 ld_fragT(const short* base, int col0, int k0, int ldk) {
    const int lane = threadIdx.x & 63;
    const short* p = base + (k0 + ((lane >> 4) << 3)) * ldk + col0 + (lane & 15);
    bf16x8 r;
    #pragma unroll
    for (int i = 0; i < 8; ++i) r[i] = p[i * ldk];
    return r;
}

// ---------------- QKV projection (hi/lo split bf16 MFMA): y = x @ W^T ----------------
__global__ __launch_bounds__(256) void gemm_qkv(const float* __restrict__ x,
    const float* __restrict__ Wq, const float* __restrict__ Wk, const float* __restrict__ Wv,
    float* __restrict__ q, float* __restrict__ k, short* __restrict__ vbf)
{
    const int which = blockIdx.z;
    const float* W = (which == 0) ? Wq : ((which == 1) ? Wk : Wv);
    __shared__ short Ah[128][40];
    __shared__ short Alo[128][40];
    __shared__ short Bh[128][40];
    __shared__ short Blo[128][40];
    const int t = threadIdx.x;
    const int lane = t & 63, wave = t >> 6;
    const int wr = wave >> 1, wc = wave & 1;
    const int row0 = blockIdx.x * 128, col0 = blockIdx.y * 128;
    f32x4 acc[4][4];
    #pragma unroll
    for (int m = 0; m < 4; ++m)
        #pragma unroll
        for (int n = 0; n < 4; ++n) { f32x4 z = {0.f, 0.f, 0.f, 0.f}; acc[m][n] = z; }
    for (int k0 = 0; k0 < DIM_; k0 += 32) {
        #pragma unroll
        for (int r = 0; r < 4; ++r) {
            int idx = t + r * 256;
            int row = idx >> 3, c4 = (idx & 7) << 2;
            float4 av = *(const float4*)(x + (size_t)(row0 + row) * DIM_ + k0 + c4);
            float4 bv = *(const float4*)(W + (size_t)(col0 + row) * DIM_ + k0 + c4);
            float af[4] = {av.x, av.y, av.z, av.w};
            float bf_[4] = {bv.x, bv.y, bv.z, bv.w};
            #pragma unroll
            for (int u = 0; u < 4; ++u) {
                short h = f2bf(af[u]);
                Ah[row][c4 + u] = h;
                Alo[row][c4 + u] = f2bf(af[u] - bf2f(h));
                short g = f2bf(bf_[u]);
                Bh[row][c4 + u] = g;
                Blo[row][c4 + u] = f2bf(bf_[u] - bf2f(g));
            }
        }
        __syncthreads();
        #pragma unroll
        for (int m = 0; m < 4; ++m) {
            bf16x8 ah = ld_frag(&Ah[0][0], wr * 64 + m * 16, 0, 40);
            bf16x8 al = ld_frag(&Alo[0][0], wr * 64 + m * 16, 0, 40);
            #pragma unroll
            for (int n = 0; n < 4; ++n) {
                bf16x8 bh = ld_frag(&Bh[0][0], wc * 64 + n * 16, 0, 40);
                bf16x8 bl = ld_frag(&Blo[0][0], wc * 64 + n * 16, 0, 40);
                acc[m][n] = MFMA16(ah, bh, acc[m][n]);
                acc[m][n] = MFMA16(ah, bl, acc[m][n]);
                acc[m][n] = MFMA16(al, bh, acc[m][n]);
            }
        }
        __syncthreads();
    }
    const float sc = (which == 2) ? 1.0f : QK_SCALE;
    #pragma unroll
    for (int m = 0; m < 4; ++m)
        #pragma unroll
        for (int n = 0; n < 4; ++n)
            #pragma unroll
            for (int i = 0; i < 4; ++i) {
                int gr = row0 + wr * 64 + m * 16 + ((lane >> 4) << 2) + i;
                int gc = col0 + wc * 64 + n * 16 + (lane & 15);
                int b = gr >> 11, nn = gr & 2047, h = gc >> 6, d = gc & 63;
                size_t oi = (((size_t)(b * H_ + h)) * N_ + nn) * D_ + d;
                float val = acc[m][n][i] * sc;
                if (which == 0) q[oi] = val;
                else if (which == 1) k[oi] = val;
                else vbf[oi] = f2bf(val);
            }
}

// ---------------- omega transpose: omT[d][m] = omega[m][d] ----------------
__global__ void tr_omega(const float* __restrict__ om, float* __restrict__ omT) {
    int idx = blockIdx.x * 256 + threadIdx.x;  // 0..8191
    int d = idx >> 7, m = idx & 127;
    omT[idx] = om[m * 64 + d];
}

// ---------------- phi: one wave per row, 2 features per lane ----------------
__global__ __launch_bounds__(256) void phi2(const float* __restrict__ qk,
    const float* __restrict__ omT, short* __restrict__ phib,
    float* __restrict__ lp_out, float* __restrict__ partmax, int is_query)
{
    const int wave = threadIdx.x >> 6, lane = threadIdx.x & 63;
    const int row = blockIdx.x * 4 + wave;
    __shared__ float qs[4][64];
    qs[wave][lane] = qk[(size_t)row * 64 + lane];
    __syncthreads();
    float ss = 0.f, p0 = 0.f, p1 = 0.f;
    #pragma unroll 8
    for (int d = 0; d < 64; ++d) {
        float qv = qs[wave][d];
        ss += qv * qv;
        p0 += qv * omT[d * 128 + lane];
        p1 += qv * omT[d * 128 + 64 + lane];
    }
    float lp0 = p0 - 0.5f * ss, lp1 = p1 - 0.5f * ss;
    float mx = fmaxf(lp0, lp1);
    #pragma unroll
    for (int off = 1; off < 64; off <<= 1) mx = fmaxf(mx, __shfl_xor(mx, off));
    if (is_query) {
        phib[(size_t)row * 128 + lane] = f2bf(expf(lp0 - mx) * INV_SQRT_M + 1e-4f);
        phib[(size_t)row * 128 + lane + 64] = f2bf(expf(lp1 - mx) * INV_SQRT_M + 1e-4f);
    } else {
        lp_out[(size_t)row * 128 + lane] = lp0;
        lp_out[(size_t)row * 128 + lane + 64] = lp1;
        if (lane == 0) partmax[row] = mx;
    }
}

__global__ void gmax_kernel(const float* __restrict__ partmax, float* __restrict__ gmax) {
    float m = -3.402823466e38f;
    for (int i = threadIdx.x; i < B_ * H_ * N_; i += 256) m = fmaxf(m, partmax[i]);
    #pragma unroll
    for (int off = 1; off < 64; off <<= 1) m = fmaxf(m, __shfl_xor(m, off));
    __shared__ float w[4];
    if ((threadIdx.x & 63) == 0) w[threadIdx.x >> 6] = m;
    __syncthreads();
    if (threadIdx.x == 0) gmax[0] = fmaxf(fmaxf(w[0], w[1]), fmaxf(w[2], w[3]));
}

__global__ __launch_bounds__(256) void phik_exp(const float* __restrict__ lp,
    const float* __restrict__ gmax, short* __restrict__ phi_k)
{
    const float g = gmax[0];
    int i = blockIdx.x * 256 + threadIdx.x;  // one float4 group each; grid covers exactly
    float4 v = *(const float4*)(lp + (size_t)i * 4);
    bf16x4 o;
    o[0] = f2bf(expf(v.x - g) * INV_SQRT_M + 1e-4f);
    o[1] = f2bf(expf(v.y - g) * INV_SQRT_M + 1e-4f);
    o[2] = f2bf(expf(v.z - g) * INV_SQRT_M + 1e-4f);
    o[3] = f2bf(expf(v.w - g) * INV_SQRT_M + 1e-4f);
    *(bf16x4*)(phi_k + (size_t)i * 4) = o;
}

// ---------------- per-chunk KV sums, TRANSPOSED: ST[d][m] = sum_n v[n][d] pk[n][m] ----------------
__global__ __launch_bounds__(256) void chunk_kv_mfma(const short* __restrict__ phi_k,
    const short* __restrict__ v_bf, float* __restrict__ S, float* __restrict__ ksum)
{
    __shared__ short pk_l[64][136];
    __shared__ short v_l[64][72];
    const int t = threadIdx.x, lane = t & 63, wave = t >> 6;
    const int wr = wave >> 1, wc = wave & 1;
    const int bh = blockIdx.x >> 5, j = blockIdx.x & 31;
    const size_t prow = (size_t)bh * N_ + (j << 6);
    #pragma unroll
    for (int it = 0; it < 4; ++it) {
        int idx = t + it * 256;
        int r = idx >> 4, c8 = (idx & 15) << 3;
        *(bf16x8*)&pk_l[r][c8] = *(const bf16x8*)(phi_k + (prow + r) * 128 + c8);
    }
    #pragma unroll
    for (int it = 0; it < 2; ++it) {
        int idx = t + it * 256;
        int r = idx >> 3, c8 = (idx & 7) << 3;
        *(bf16x8*)&v_l[r][c8] = *(const bf16x8*)(v_bf + (prow + r) * 64 + c8);
    }
    __syncthreads();
    // output 64(d) x 128(m); wave quadrant: rows wr*32, cols wc*64
    f32x4 acc[2][4];
    #pragma unroll
    for (int mi = 0; mi < 2; ++mi)
        #pragma unroll
        for (int ni = 0; ni < 4; ++ni) { f32x4 z = {0.f, 0.f, 0.f, 0.f}; acc[mi][ni] = z; }
    #pragma unroll
    for (int ks = 0; ks < 2; ++ks) {
        bf16x8 a0 = ld_fragT(&v_l[0][0], wr * 32, ks * 32, 72);       // A = v^T
        bf16x8 a1 = ld_fragT(&v_l[0][0], wr * 32 + 16, ks * 32, 72);
        #pragma unroll
        for (int ni = 0; ni < 4; ++ni) {
            bf16x8 bb = ld_fragT(&pk_l[0][0], wc * 64 + ni * 16, ks * 32, 136);  // B = pk (K x N)
            acc[0][ni] = MFMA16(a0, bb, acc[0][ni]);
            acc[1][ni] = MFMA16(a1, bb, acc[1][ni]);
        }
    }
    const size_t sbase = ((size_t)blockIdx.x) << 13;  // (bh*32+j)*8192
    #pragma unroll
    for (int mi = 0; mi < 2; ++mi)
        #pragma unroll
        for (int ni = 0; ni < 4; ++ni)
            #pragma unroll
            for (int i = 0; i < 4; ++i) {
                int row = wr * 32 + mi * 16 + ((lane >> 4) << 2) + i;  // d
                int col = wc * 64 + ni * 16 + (lane & 15);             // m
                S[sbase + (size_t)row * 128 + col] = acc[mi][ni][i];
            }
    if (t < 128) {
        float s = 0.f;
        #pragma unroll 8
        for (int n = 0; n < 64; ++n) s += bf2f(pk_l[n][t]);
        ksum[((size_t)blockIdx.x) * 128 + t] = s;
    }
}

// ---------------- exclusive prefix over chunks; S -> bf16 ----------------
__global__ __launch_bounds__(256) void prefix_scan(const float* __restrict__ S,
    const float* __restrict__ ksum, short* __restrict__ STbf, float* __restrict__ kpre)
{
    const int bh = blockIdx.x, y = blockIdx.y, t = threadIdx.x;
    if (y < 32) {
        int e = y * 256 + t;  // element (d*128+m)
        size_t base = (size_t)bh * NC_ * 8192 + e;
        float run = 0.f;
        #pragma unroll
        for (int j = 0; j < NC_; ++j) {
            float val = S[base + (size_t)j * 8192];
            STbf[base + (size_t)j * 8192] = f2bf(run);
            run += val;
        }
    } else if (t < 128) {
        size_t base = (size_t)bh * NC_ * 128 + t;
        float run = 0.f;
        #pragma unroll
        for (int j = 0; j < NC_; ++j) {
            float val = ksum[base + (size_t)j * 128];
            kpre[base + (size_t)j * 128] = run;
            run += val;
        }
    }
}

// ---------------- per-chunk output (MFMA) ----------------
__global__ __launch_bounds__(256) void chunk_out_mfma(
    const short* __restrict__ phi_q, const short* __restrict__ phi_k,
    const short* __restrict__ v_bf, const short* __restrict__ STbf,
    const float* __restrict__ kpre, short* __restrict__ o_hi, short* __restrict__ o_lo)
{
    __shared__ short pq_l[64][136];
    __shared__ short pkst_l[64][136];  // pk first, ST after barrier2
    __shared__ short v_l[64][72];
    __shared__ short a_l[64][72];
    __shared__ float rsum[64][8];
    __shared__ float den[64];
    __shared__ float ksp_l[128];
    const int t = threadIdx.x, lane = t & 63, wave = t >> 6;
    const int wr = wave >> 1, wc = wave & 1;
    const int bh = blockIdx.x >> 5, j = blockIdx.x & 31;
    const int n0 = j << 6;
    const size_t prow = (size_t)bh * N_ + n0;
    #pragma unroll
    for (int it = 0; it < 4; ++it) {
        int idx = t + it * 256;
        int r = idx >> 4, c8 = (idx & 15) << 3;
        *(bf16x8*)&pq_l[r][c8] = *(const bf16x8*)(phi_q + (prow + r) * 128 + c8);
        *(bf16x8*)&pkst_l[r][c8] = *(const bf16x8*)(phi_k + (prow + r) * 128 + c8);
    }
    #pragma unroll
    for (int it = 0; it < 2; ++it) {
        int idx = t + it * 256;
        int r = idx >> 3, c8 = (idx & 7) << 3;
        *(bf16x8*)&v_l[r][c8] = *(const bf16x8*)(v_bf + (prow + r) * 64 + c8);
    }
    if (t < 128) ksp_l[t] = kpre[((size_t)bh * NC_ + j) * 128 + t];
    __syncthreads();
    // ---- QK^T: each wave a 32x32 quadrant ----
    f32x4 qk[2][2];
    #pragma unroll
    for (int mi = 0; mi < 2; ++mi)
        #pragma unroll
        for (int ni = 0; ni < 2; ++ni) { f32x4 z = {0.f, 0.f, 0.f, 0.f}; qk[mi][ni] = z; }
    #pragma unroll
    for (int ks = 0; ks < 4; ++ks) {
        bf16x8 a0 = ld_frag(&pq_l[0][0], wr * 32, ks * 32, 136);
        bf16x8 a1 = ld_frag(&pq_l[0][0], wr * 32 + 16, ks * 32, 136);
        bf16x8 b0 = ld_frag(&pkst_l[0][0], wc * 32, ks * 32, 136);
        bf16x8 b1 = ld_frag(&pkst_l[0][0], wc * 32 + 16, ks * 32, 136);
        qk[0][0] = MFMA16(a0, b0, qk[0][0]);
        qk[0][1] = MFMA16(a0, b1, qk[0][1]);
        qk[1][0] = MFMA16(a1, b0, qk[1][0]);
        qk[1][1] = MFMA16(a1, b1, qk[1][1]);
    }
    // ---- mask + A->bf16 + row-sums ----
    #pragma unroll
    for (int mi = 0; mi < 2; ++mi)
        #pragma unroll
        for (int i = 0; i < 4; ++i) {
            int row = wr * 32 + mi * 16 + ((lane >> 4) << 2) + i;
            float part = 0.f;
            #pragma unroll
            for (int ni = 0; ni < 2; ++ni) {
                int col = wc * 32 + ni * 16 + (lane & 15);
                float val = (col <= row) ? qk[mi][ni][i] : 0.f;
                a_l[row][col] = f2bf(val);
                part += val;
            }
            part += __shfl_xor(part, 1);
            part += __shfl_xor(part, 2);
            part += __shfl_xor(part, 4);
            part += __shfl_xor(part, 8);
            if ((lane & 15) == 0) rsum[row][wc] = part;
        }
    // ---- denominator ksum-prefix dot partials ----
    {
        int row = t & 63, qq = t >> 6;
        float s = 0.f;
        #pragma unroll
        for (int m = 0; m < 32; ++m) s += bf2f(pq_l[row][qq * 32 + m]) * ksp_l[qq * 32 + m];
        rsum[row][4 + qq] = s;
    }
    __syncthreads();
    // ---- restage ST into pk region; finalize den ----
    #pragma unroll
    for (int it = 0; it < 4; ++it) {
        int idx = t + it * 256;
        int r = idx >> 4, c8 = (idx & 15) << 3;
        *(bf16x8*)&pkst_l[r][c8] =
            *(const bf16x8*)(STbf + (((size_t)bh * NC_ + j) << 13) + r * 128 + c8);
    }
    if (t < 64) {
        float s = rsum[t][0] + rsum[t][1] + rsum[t][4] + rsum[t][5] + rsum[t][6] + rsum[t][7];
        den[t] = 1.0f / (s + 1e-6f);
    }
    __syncthreads();
    // ---- O = A_masked @ V + pq @ Sp ----
    f32x4 oa[2][2];
    #pragma unroll
    for (int mi = 0; mi < 2; ++mi)
        #pragma unroll
        for (int ni = 0; ni < 2; ++ni) { f32x4 z = {0.f, 0.f, 0.f, 0.f}; oa[mi][ni] = z; }
    #pragma unroll
    for (int ks = 0; ks < 2; ++ks) {
        bf16x8 a0 = ld_frag(&a_l[0][0], wr * 32, ks * 32, 72);
        bf16x8 a1 = ld_frag(&a_l[0][0], wr * 32 + 16, ks * 32, 72);
        #pragma unroll
        for (int ni = 0; ni < 2; ++ni) {
            bf16x8 bb = ld_fragT(&v_l[0][0], wc * 32 + ni * 16, ks * 32, 72);  // B = v (K x N)
            oa[0][ni] = MFMA16(a0, bb, oa[0][ni]);
            oa[1][ni] = MFMA16(a1, bb, oa[1][ni]);
        }
    }
    #pragma unroll
    for (int ks = 0; ks < 4; ++ks) {
        bf16x8 a0 = ld_frag(&pq_l[0][0], wr * 32, ks * 32, 136);
        bf16x8 a1 = ld_frag(&pq_l[0][0], wr * 32 + 16, ks * 32, 136);
        #pragma unroll
        for (int ni = 0; ni < 2; ++ni) {
            bf16x8 bb = ld_frag(&pkst_l[0][0], wc * 32 + ni * 16, ks * 32, 136);  // ST = B^T
            oa[0][ni] = MFMA16(a0, bb, oa[0][ni]);
            oa[1][ni] = MFMA16(a1, bb, oa[1][ni]);
        }
    }
    const int b_ = bh >> 3, h = bh & 7;
    #pragma unroll
    for (int mi = 0; mi < 2; ++mi)
        #pragma unroll
        for (int ni = 0; ni < 2; ++ni)
            #pragma unroll
            for (int i = 0; i < 4; ++i) {
                int row = wr * 32 + mi * 16 + ((lane >> 4) << 2) + i;
                int col = wc * 32 + ni * 16 + (lane & 15);
                float val = oa[mi][ni][i] * den[row];
                size_t oi = ((size_t)b_ * N_ + n0 + row) * 512 + h * 64 + col;
                short hi = f2bf(val);
                o_hi[oi] = hi;
                o_lo[oi] = f2bf(val - bf2f(hi));
            }
}

// ---------------- output projection (hi/lo split): out = o @ Wo^T + bo ----------------
__global__ __launch_bounds__(256) void gemm_out(const short* __restrict__ ohi,
    const short* __restrict__ olo, const float* __restrict__ Wo,
    const float* __restrict__ bo, float* __restrict__ out)
{
    __shared__ short Ah[128][40];
    __shared__ short Alo[128][40];
    __shared__ short Bh[128][40];
    __shared__ short Blo[128][40];
    const int t = threadIdx.x;
    const int lane = t & 63, wave = t >> 6;
    const int wr = wave >> 1, wc = wave & 1;
    const int row0 = blockIdx.x * 128, col0 = blockIdx.y * 128;
    f32x4 acc[4][4];
    #pragma unroll
    for (int m = 0; m < 4; ++m)
        #pragma unroll
        for (int n = 0; n < 4; ++n) { f32x4 z = {0.f, 0.f, 0.f, 0.f}; acc[m][n] = z; }
    for (int k0 = 0; k0 < 512; k0 += 32) {
        #pragma unroll
        for (int r = 0; r < 2; ++r) {
            int idx = t + r * 256;
            int row = idx >> 2, c8 = (idx & 3) << 3;
            *(bf16x8*)&Ah[row][c8] = *(const bf16x8*)(ohi + (size_t)(row0 + row) * 512 + k0 + c8);
            *(bf16x8*)&Alo[row][c8] = *(const bf16x8*)(olo + (size_t)(row0 + row) * 512 + k0 + c8);
        }
        #pragma unroll
        for (int r = 0; r < 4; ++r) {
            int idx = t + r * 256;
            int row = idx >> 3, c4 = (idx & 7) << 2;
            float4 bv = *(const float4*)(Wo + (size_t)(col0 + row) * 512 + k0 + c4);
            float bf_[4] = {bv.x, bv.y, bv.z, bv.w};
            #pragma unroll
            for (int u = 0; u < 4; ++u) {
                short g = f2bf(bf_[u]);
                Bh[row][c4 + u] = g;
                Blo[row][c4 + u] = f2bf(bf_[u] - bf2f(g));
            }
        }
        __syncthreads();
        #pragma unroll
        for (int m = 0; m < 4; ++m) {
            bf16x8 ah = ld_frag(&Ah[0][0], wr * 64 + m * 16, 0, 40);
            bf16x8 al = ld_frag(&Alo[0][0], wr * 64 + m * 16, 0, 40);
            #pragma unroll
            for (int n = 0; n < 4; ++n) {
                bf16x8 bh = ld_frag(&Bh[0][0], wc * 64 + n * 16, 0, 40);
                bf16x8 bl = ld_frag(&Blo[0][0], wc * 64 + n * 16, 0, 40);
                acc[m][n] = MFMA16(ah, bh, acc[m][n]);
                acc[m][n] = MFMA16(ah, bl, acc[m][n]);
                acc[m][n] = MFMA16(al, bh, acc[m][n]);
            }
        }
        __syncthreads();
    }
    #pragma unroll
    for (int m = 0; m < 4; ++m)
        #pragma unroll
        for (int n = 0; n < 4; ++n)
            #pragma unroll
            for (int i = 0; i < 4; ++i) {
                int gr = row0 + wr * 64 + m * 16 + ((lane >> 4) << 2) + i;
                int gc = col0 + wc * 64 + n * 16 + (lane & 15);
                out[(size_t)gr * 512 + gc] = acc[m][n][i] + bo[gc];
            }
}

extern "C" void kernel_launch(void* const* d_in, const int* in_sizes, int n_in,
                              void* d_out, int out_size, void* d_ws, size_t ws_size,
                              hipStream_t stream) {
    const float* x     = (const float*)d_in[0];
    const float* omega = (const float*)d_in[1];
    const float* Wq    = (const float*)d_in[2];
    const float* Wk    = (const float*)d_in[3];
    const float* Wv    = (const float*)d_in[4];
    const float* Wo    = (const float*)d_in[5];
    const float* bo    = (const float*)d_in[6];
    float* out = (float*)d_out;

    char* w = (char*)d_ws;
    float* q    = (float*)(w);                       // 8 MB
    float* kk   = (float*)(w + (8ull << 20));        // 8 MB
    float* lpST = (float*)(w + (16ull << 20));       // 16 MB  (lp, then reused as S)
    short* vbf  = (short*)(w + (32ull << 20));       // 4 MB
    short* phiq = (short*)(w + (36ull << 20));       // 8 MB
    short* phik = (short*)(w + (44ull << 20));       // 8 MB
    short* STbf = (short*)(w + (52ull << 20));       // 8 MB
    short* ohi  = (short*)(w + (60ull << 20));       // 4 MB
    short* olo  = (short*)(w + (64ull << 20));       // 4 MB
    float* ksum = (float*)(w + (68ull << 20));                      // 256 KB
    float* kpre = (float*)(w + (68ull << 20) + (256ull << 10));     // 256 KB
    float* pmax = (float*)(w + (68ull << 20) + (512ull << 10));     // 128 KB
    float* gmx  = (float*)(w + (68ull << 20) + (640ull << 10));     // 4 B
    float* omT  = (float*)(w + (68ull << 20) + (644ull << 10));     // 32 KB

    tr_omega<<<32, 256, 0, stream>>>(omega, omT);
    gemm_qkv<<<dim3(32, 4, 3), 256, 0, stream>>>(x, Wq, Wk, Wv, q, kk, vbf);
    phi2<<<8192, 256, 0, stream>>>(q, omT, phiq, nullptr, nullptr, 1);
    phi2<<<8192, 256, 0, stream>>>(kk, omT, nullptr, lpST, pmax, 0);
    gmax_kernel<<<1, 256, 0, stream>>>(pmax, gmx);
    phik_exp<<<4096, 256, 0, stream>>>(lpST, gmx, phik);
    chunk_kv_mfma<<<512, 256, 0, stream>>>(phik, vbf, lpST, ksum);
    prefix_scan<<<dim3(16, 33), 256, 0, stream>>>(lpST, ksum, STbf, kpre);
    chunk_out_mfma<<<512, 256, 0, stream>>>(phiq, phik, vbf, STbf, kpre, ohi, olo);
    gemm_out<<<dim3(32, 4), 256, 0, stream>>>(ohi, olo, Wo, bo, out);
}

// Round 3
// 220.466 us; speedup vs baseline: 3.8536x; 1.1571x over previous
//
#include <hip/hip_runtime.h>
#include <math.h>

#define B_ 2
#define N_ 2048
#define DIM_ 512
#define H_ 8
#define D_ 64
#define M_ 128
#define NC_ 32
#define C_ 64

#define INV_SQRT_M 0.08838834764831845f
#define QK_SCALE 0.35355339059327373f
#define NCOLS_ 3584

typedef __attribute__((ext_vector_type(8))) short bf16x8;
typedef __attribute__((ext_vector_type(4))) short bf16x4;
typedef __attribute__((ext_vector_type(4))) float f32x4;

#define MFMA16(a, b, c) __builtin_amdgcn_mfma_f32_16x16x32_bf16((a), (b), (c), 0, 0, 0)

__device__ __forceinline__ short f2bf(float f) {
    union { float f; unsigned u; } x; x.f = f;
    unsigned r = (x.u + 0x7FFFu + ((x.u >> 16) & 1u)) >> 16;
    return (short)r;
}
__device__ __forceinline__ float bf2f(short s) {
    union { unsigned u; float f; } x; x.u = ((unsigned)(unsigned short)s) << 16;
    return x.f;
}

// async global->LDS 16B copy: LDS dst = (wave-uniform base) + lane*16
__device__ __forceinline__ void gl16(void* lds, const void* g) {
    __builtin_amdgcn_global_load_lds(
        (const __attribute__((address_space(1))) unsigned int*)g,
        (__attribute__((address_space(3))) unsigned int*)lds,
        16, 0, 0);
}

// fragment load from row-major LDS tile [rows][ldk] bf16 (A or B^T form)
__device__ __forceinline__ bf16x8 ld_frag(const short* base, int row0, int k0, int ldk) {
    const int lane = threadIdx.x & 63;
    return *(const bf16x8*)(base + (row0 + (lane & 15)) * ldk + k0 + ((lane >> 4) << 3));
}
// strided (transposed) fragment load: operand stored [K][cols] row-major
__device__ __forceinline__ bf16x8 ld_fragT(const short* base, int col0, int k0, int ldk) {
    const int lane = threadIdx.x & 63;
    const short* p = base + (k0 + ((lane >> 4) << 3)) * ldk + col0 + (lane & 15);
    bf16x8 r;
    #pragma unroll
    for (int i = 0; i < 8; ++i) r[i] = p[i * ldk];
    return r;
}

// ---------------- prep: elementwise hi/lo split (x, Wq, Wk, Wv, Wo) ----------------
__global__ __launch_bounds__(256) void split_scale(
    const float* __restrict__ x, const float* __restrict__ Wq, const float* __restrict__ Wk,
    const float* __restrict__ Wv, const float* __restrict__ Wo,
    short* __restrict__ xh, short* __restrict__ xl,
    short* __restrict__ Wch, short* __restrict__ Wcl,
    short* __restrict__ Wohi, short* __restrict__ Wolo)
{
    const int z = blockIdx.z;
    const float* src; short *dh, *dl; int nelem; float sc;
    switch (z) {
      case 0:  src = x;  dh = xh;   dl = xl;   nelem = 4096*512; sc = 1.f; break;
      case 1:  src = Wq; dh = Wch;  dl = Wcl;  nelem = 512*512;  sc = QK_SCALE; break;
      case 2:  src = Wk; dh = Wch + 512*512;  dl = Wcl + 512*512;  nelem = 512*512; sc = QK_SCALE; break;
      case 3:  src = Wv; dh = Wch + 1024*512; dl = Wcl + 1024*512; nelem = 512*512; sc = 1.f; break;
      default: src = Wo; dh = Wohi; dl = Wolo; nelem = 512*512;  sc = 1.f; break;
    }
    int i4 = blockIdx.x * 256 + threadIdx.x;
    if (i4 * 4 >= nelem) return;
    float4 v = *(const float4*)(src + (size_t)i4 * 4);
    float a[4] = {v.x * sc, v.y * sc, v.z * sc, v.w * sc};
    bf16x4 hi, lo;
    #pragma unroll
    for (int u = 0; u < 4; ++u) {
        short h = f2bf(a[u]);
        hi[u] = h;
        lo[u] = f2bf(a[u] - bf2f(h));
    }
    *(bf16x4*)(dh + (size_t)i4 * 4) = hi;
    *(bf16x4*)(dl + (size_t)i4 * 4) = lo;
}

// ---------------- prep: Wcomb rows 1536.. = omega @ (W*scale) per head, hi/lo ----------------
__global__ __launch_bounds__(256) void prep_omw(const float* __restrict__ omega,
    const float* __restrict__ Wq, const float* __restrict__ Wk,
    short* __restrict__ Wch, short* __restrict__ Wcl)
{
    __shared__ float Ws[64][65];
    __shared__ float om[128][64];
    const int t = threadIdx.x;
    const int qk = blockIdx.x >> 6, h = (blockIdx.x >> 3) & 7, cb = blockIdx.x & 7;
    const int col0 = cb * 64;
    const float* W = qk ? Wk : Wq;
    for (int i = t; i < 64 * 64; i += 256) {
        int d = i >> 6, c = i & 63;
        Ws[d][c] = W[(size_t)(h * 64 + d) * 512 + col0 + c] * QK_SCALE;
    }
    for (int i = t; i < 128 * 64; i += 256) om[i >> 6][i & 63] = omega[i];
    __syncthreads();
    const int lane = t & 63, w = t >> 6;
    const int c = col0 + lane;
    float Wcol[64];
    #pragma unroll
    for (int d = 0; d < 64; ++d) Wcol[d] = Ws[d][lane];
    for (int mi = 0; mi < 32; ++mi) {
        int m = w * 32 + mi;
        float acc = 0.f;
        #pragma unroll
        for (int d = 0; d < 64; d += 4) {
            float4 o4 = *(const float4*)&om[m][d];
            acc += o4.x * Wcol[d] + o4.y * Wcol[d+1] + o4.z * Wcol[d+2] + o4.w * Wcol[d+3];
        }
        int row = 1536 + qk * 1024 + h * 128 + m;
        short hi = f2bf(acc);
        Wch[(size_t)row * 512 + c] = hi;
        Wcl[(size_t)row * 512 + c] = f2bf(acc - bf2f(hi));
    }
}

// ---------------- fused GEMM: [4096 x 3584] = x @ Wcomb^T (hi/lo 3-pass MFMA) ----------------
// col sections: [0,512) q->ssq only; [512,1024) k->ssq; [1024,1536) v->bf16;
//               [1536,2560) projq f32; [2560,3584) projk f32
__global__ __launch_bounds__(256) void gemm_fused(
    const short* __restrict__ xh, const short* __restrict__ xl,
    const short* __restrict__ Wch, const short* __restrict__ Wcl,
    float* __restrict__ projq, float* __restrict__ projk,
    short* __restrict__ vbf, float* __restrict__ ssqbuf)
{
    __shared__ short Ah[128 * 32];
    __shared__ short Al[128 * 32];
    __shared__ short Bh[128 * 32];
    __shared__ short Bl[128 * 32];
    const int t = threadIdx.x, lane = t & 63, wave = t >> 6;
    const int wr = wave >> 1, wc = wave & 1;
    const int row0 = blockIdx.x * 128;
    const int by = blockIdx.y;
    const int col0 = by * 128;
    const int l_row = lane >> 2, l_col = (lane & 3) << 3;
    f32x4 acc[4][4];
    #pragma unroll
    for (int m = 0; m < 4; ++m)
        #pragma unroll
        for (int n = 0; n < 4; ++n) { f32x4 z = {0.f, 0.f, 0.f, 0.f}; acc[m][n] = z; }
    for (int k0 = 0; k0 < 512; k0 += 32) {
        #pragma unroll
        for (int sub = 0; sub < 2; ++sub) {
            int s = wave * 2 + sub;
            int gr = s * 16 + l_row;
            size_t ga = (size_t)(row0 + gr) * 512 + k0 + l_col;
            size_t gb = (size_t)(col0 + gr) * 512 + k0 + l_col;
            gl16(&Ah[s * 512], xh + ga);
            gl16(&Al[s * 512], xl + ga);
            gl16(&Bh[s * 512], Wch + gb);
            gl16(&Bl[s * 512], Wcl + gb);
        }
        __syncthreads();
        bf16x8 bh[4], bl[4];
        #pragma unroll
        for (int n = 0; n < 4; ++n) {
            bh[n] = ld_frag(Bh, wc * 64 + n * 16, 0, 32);
            bl[n] = ld_frag(Bl, wc * 64 + n * 16, 0, 32);
        }
        #pragma unroll
        for (int m = 0; m < 4; ++m) {
            bf16x8 ah = ld_frag(Ah, wr * 64 + m * 16, 0, 32);
            bf16x8 al = ld_frag(Al, wr * 64 + m * 16, 0, 32);
            #pragma unroll
            for (int n = 0; n < 4; ++n) {
                acc[m][n] = MFMA16(al, bh[n], acc[m][n]);
                acc[m][n] = MFMA16(ah, bl[n], acc[m][n]);
                acc[m][n] = MFMA16(ah, bh[n], acc[m][n]);
            }
        }
        __syncthreads();
    }
    if (by < 8) {
        // ssq for q (by<4) or k (by>=4); head = (by*2+wc)&7, per-wave 64 cols = 1 head
        const int qk = by >> 2;
        const int head = (by * 2 + wc) & 7;
        #pragma unroll
        for (int m = 0; m < 4; ++m)
            #pragma unroll
            for (int i = 0; i < 4; ++i) {
                float s = 0.f;
                #pragma unroll
                for (int n = 0; n < 4; ++n) { float v2 = acc[m][n][i]; s += v2 * v2; }
                s += __shfl_xor(s, 1); s += __shfl_xor(s, 2);
                s += __shfl_xor(s, 4); s += __shfl_xor(s, 8);
                if ((lane & 15) == 0) {
                    int row = row0 + wr * 64 + m * 16 + ((lane >> 4) << 2) + i;
                    int b = row >> 11, nn = row & 2047;
                    ssqbuf[qk * 32768 + (b * 8 + head) * 2048 + nn] = s;
                }
            }
    } else if (by < 12) {
        #pragma unroll
        for (int m = 0; m < 4; ++m)
            #pragma unroll
            for (int n = 0; n < 4; ++n)
                #pragma unroll
                for (int i = 0; i < 4; ++i) {
                    int row = row0 + wr * 64 + m * 16 + ((lane >> 4) << 2) + i;
                    int gc = col0 + wc * 64 + n * 16 + (lane & 15);
                    int c = gc - 1024, h = c >> 6, d = c & 63;
                    int b = row >> 11, nn = row & 2047;
                    vbf[((size_t)(b * 8 + h) * 2048 + nn) * 64 + d] = f2bf(acc[m][n][i]);
                }
    } else {
        float* dst = (by < 20) ? projq : projk;
        const int coff = (by < 20) ? 1536 : 2560;
        #pragma unroll
        for (int m = 0; m < 4; ++m)
            #pragma unroll
            for (int n = 0; n < 4; ++n)
                #pragma unroll
                for (int i = 0; i < 4; ++i) {
                    int row = row0 + wr * 64 + m * 16 + ((lane >> 4) << 2) + i;
                    int pc = col0 - coff + wc * 64 + n * 16 + (lane & 15);
                    dst[(size_t)row * 1024 + pc] = acc[m][n][i];
                }
    }
}

// ---------------- phi: elementwise over proj rows ----------------
__global__ __launch_bounds__(256) void phi_all(
    const float* __restrict__ projq, float* __restrict__ projk,
    const float* __restrict__ ssqbuf, short* __restrict__ phiq, float* __restrict__ pmax)
{
    const int wave = threadIdx.x >> 6, lane = threadIdx.x & 63;
    const int g = blockIdx.x * 4 + wave;          // (b*8+h)*2048 + n
    const int b = g >> 14, h = (g >> 11) & 7, n = g & 2047;
    const size_t r = (size_t)b * 2048 + n;
    const size_t pbase = r * 1024 + h * 128 + lane;
    // query
    float sq = ssqbuf[g] * 0.5f;
    float lp0 = projq[pbase] - sq;
    float lp1 = projq[pbase + 64] - sq;
    float mx = fmaxf(lp0, lp1);
    #pragma unroll
    for (int off = 1; off < 64; off <<= 1) mx = fmaxf(mx, __shfl_xor(mx, off));
    phiq[(size_t)g * 128 + lane]      = f2bf(expf(lp0 - mx) * INV_SQRT_M + 1e-4f);
    phiq[(size_t)g * 128 + lane + 64] = f2bf(expf(lp1 - mx) * INV_SQRT_M + 1e-4f);
    // key: write lp back in place, record row max
    float sk = ssqbuf[32768 + g] * 0.5f;
    float k0 = projk[pbase] - sk;
    float k1 = projk[pbase + 64] - sk;
    projk[pbase] = k0;
    projk[pbase + 64] = k1;
    float mk = fmaxf(k0, k1);
    #pragma unroll
    for (int off = 1; off < 64; off <<= 1) mk = fmaxf(mk, __shfl_xor(mk, off));
    if (lane == 0) pmax[g] = mk;
}

__global__ void gmax_kernel(const float* __restrict__ partmax, float* __restrict__ gmax) {
    float m = -3.402823466e38f;
    for (int i = threadIdx.x; i < B_ * H_ * N_; i += 256) m = fmaxf(m, partmax[i]);
    #pragma unroll
    for (int off = 1; off < 64; off <<= 1) m = fmaxf(m, __shfl_xor(m, off));
    __shared__ float w[4];
    if ((threadIdx.x & 63) == 0) w[threadIdx.x >> 6] = m;
    __syncthreads();
    if (threadIdx.x == 0) gmax[0] = fmaxf(fmaxf(w[0], w[1]), fmaxf(w[2], w[3]));
}

__global__ __launch_bounds__(256) void phik_exp(const float* __restrict__ lp,
    const float* __restrict__ gmax, short* __restrict__ phik)
{
    const float g = gmax[0];
    size_t i = ((size_t)blockIdx.x * 256 + threadIdx.x) * 4;   // over 4096*1024
    float4 v = *(const float4*)(lp + i);
    int r = (int)(i >> 10), c = (int)(i & 1023);
    int h = c >> 7, m = c & 127;
    int b = r >> 11, n = r & 2047;
    size_t o = ((size_t)(b * 8 + h) * 2048 + n) * 128 + m;
    bf16x4 ov;
    ov[0] = f2bf(expf(v.x - g) * INV_SQRT_M + 1e-4f);
    ov[1] = f2bf(expf(v.y - g) * INV_SQRT_M + 1e-4f);
    ov[2] = f2bf(expf(v.z - g) * INV_SQRT_M + 1e-4f);
    ov[3] = f2bf(expf(v.w - g) * INV_SQRT_M + 1e-4f);
    *(bf16x4*)(phik + o) = ov;
}

// ---------------- per-chunk KV sums, TRANSPOSED: ST[d][m] = sum_n v[n][d] pk[n][m] ----------------
__global__ __launch_bounds__(256) void chunk_kv_mfma(const short* __restrict__ phi_k,
    const short* __restrict__ v_bf, float* __restrict__ S, float* __restrict__ ksum)
{
    __shared__ short pk_l[64][136];
    __shared__ short v_l[64][72];
    const int t = threadIdx.x, lane = t & 63, wave = t >> 6;
    const int wr = wave >> 1, wc = wave & 1;
    const int bh = blockIdx.x >> 5, j = blockIdx.x & 31;
    const size_t prow = (size_t)bh * N_ + (j << 6);
    #pragma unroll
    for (int it = 0; it < 4; ++it) {
        int idx = t + it * 256;
        int r = idx >> 4, c8 = (idx & 15) << 3;
        *(bf16x8*)&pk_l[r][c8] = *(const bf16x8*)(phi_k + (prow + r) * 128 + c8);
    }
    #pragma unroll
    for (int it = 0; it < 2; ++it) {
        int idx = t + it * 256;
        int r = idx >> 3, c8 = (idx & 7) << 3;
        *(bf16x8*)&v_l[r][c8] = *(const bf16x8*)(v_bf + (prow + r) * 64 + c8);
    }
    __syncthreads();
    f32x4 acc[2][4];
    #pragma unroll
    for (int mi = 0; mi < 2; ++mi)
        #pragma unroll
        for (int ni = 0; ni < 4; ++ni) { f32x4 z = {0.f, 0.f, 0.f, 0.f}; acc[mi][ni] = z; }
    #pragma unroll
    for (int ks = 0; ks < 2; ++ks) {
        bf16x8 a0 = ld_fragT(&v_l[0][0], wr * 32, ks * 32, 72);
        bf16x8 a1 = ld_fragT(&v_l[0][0], wr * 32 + 16, ks * 32, 72);
        #pragma unroll
        for (int ni = 0; ni < 4; ++ni) {
            bf16x8 bb = ld_fragT(&pk_l[0][0], wc * 64 + ni * 16, ks * 32, 136);
            acc[0][ni] = MFMA16(a0, bb, acc[0][ni]);
            acc[1][ni] = MFMA16(a1, bb, acc[1][ni]);
        }
    }
    const size_t sbase = ((size_t)blockIdx.x) << 13;
    #pragma unroll
    for (int mi = 0; mi < 2; ++mi)
        #pragma unroll
        for (int ni = 0; ni < 4; ++ni)
            #pragma unroll
            for (int i = 0; i < 4; ++i) {
                int row = wr * 32 + mi * 16 + ((lane >> 4) << 2) + i;
                int col = wc * 64 + ni * 16 + (lane & 15);
                S[sbase + (size_t)row * 128 + col] = acc[mi][ni][i];
            }
    if (t < 128) {
        float s = 0.f;
        #pragma unroll 8
        for (int n = 0; n < 64; ++n) s += bf2f(pk_l[n][t]);
        ksum[((size_t)blockIdx.x) * 128 + t] = s;
    }
}

// ---------------- exclusive prefix over chunks; S -> bf16 ----------------
__global__ __launch_bounds__(256) void prefix_scan(const float* __restrict__ S,
    const float* __restrict__ ksum, short* __restrict__ STbf, float* __restrict__ kpre)
{
    const int bh = blockIdx.x, y = blockIdx.y, t = threadIdx.x;
    if (y < 32) {
        int e = y * 256 + t;
        size_t base = (size_t)bh * NC_ * 8192 + e;
        float run = 0.f;
        #pragma unroll
        for (int j = 0; j < NC_; ++j) {
            float val = S[base + (size_t)j * 8192];
            STbf[base + (size_t)j * 8192] = f2bf(run);
            run += val;
        }
    } else if (t < 128) {
        size_t base = (size_t)bh * NC_ * 128 + t;
        float run = 0.f;
        #pragma unroll
        for (int j = 0; j < NC_; ++j) {
            float val = ksum[base + (size_t)j * 128];
            kpre[base + (size_t)j * 128] = run;
            run += val;
        }
    }
}

// ---------------- per-chunk output (MFMA) ----------------
__global__ __launch_bounds__(256) void chunk_out_mfma(
    const short* __restrict__ phi_q, const short* __restrict__ phi_k,
    const short* __restrict__ v_bf, const short* __restrict__ STbf,
    const float* __restrict__ kpre, short* __restrict__ o_hi, short* __restrict__ o_lo)
{
    __shared__ short pq_l[64][136];
    __shared__ short pkst_l[64][136];
    __shared__ short v_l[64][72];
    __shared__ short a_l[64][72];
    __shared__ float rsum[64][8];
    __shared__ float den[64];
    __shared__ float ksp_l[128];
    const int t = threadIdx.x, lane = t & 63, wave = t >> 6;
    const int wr = wave >> 1, wc = wave & 1;
    const int bh = blockIdx.x >> 5, j = blockIdx.x & 31;
    const int n0 = j << 6;
    const size_t prow = (size_t)bh * N_ + n0;
    #pragma unroll
    for (int it = 0; it < 4; ++it) {
        int idx = t + it * 256;
        int r = idx >> 4, c8 = (idx & 15) << 3;
        *(bf16x8*)&pq_l[r][c8] = *(const bf16x8*)(phi_q + (prow + r) * 128 + c8);
        *(bf16x8*)&pkst_l[r][c8] = *(const bf16x8*)(phi_k + (prow + r) * 128 + c8);
    }
    #pragma unroll
    for (int it = 0; it < 2; ++it) {
        int idx = t + it * 256;
        int r = idx >> 3, c8 = (idx & 7) << 3;
        *(bf16x8*)&v_l[r][c8] = *(const bf16x8*)(v_bf + (prow + r) * 64 + c8);
    }
    if (t < 128) ksp_l[t] = kpre[((size_t)bh * NC_ + j) * 128 + t];
    __syncthreads();
    f32x4 qk[2][2];
    #pragma unroll
    for (int mi = 0; mi < 2; ++mi)
        #pragma unroll
        for (int ni = 0; ni < 2; ++ni) { f32x4 z = {0.f, 0.f, 0.f, 0.f}; qk[mi][ni] = z; }
    #pragma unroll
    for (int ks = 0; ks < 4; ++ks) {
        bf16x8 a0 = ld_frag(&pq_l[0][0], wr * 32, ks * 32, 136);
        bf16x8 a1 = ld_frag(&pq_l[0][0], wr * 32 + 16, ks * 32, 136);
        bf16x8 b0 = ld_frag(&pkst_l[0][0], wc * 32, ks * 32, 136);
        bf16x8 b1 = ld_frag(&pkst_l[0][0], wc * 32 + 16, ks * 32, 136);
        qk[0][0] = MFMA16(a0, b0, qk[0][0]);
        qk[0][1] = MFMA16(a0, b1, qk[0][1]);
        qk[1][0] = MFMA16(a1, b0, qk[1][0]);
        qk[1][1] = MFMA16(a1, b1, qk[1][1]);
    }
    #pragma unroll
    for (int mi = 0; mi < 2; ++mi)
        #pragma unroll
        for (int i = 0; i < 4; ++i) {
            int row = wr * 32 + mi * 16 + ((lane >> 4) << 2) + i;
            float part = 0.f;
            #pragma unroll
            for (int ni = 0; ni < 2; ++ni) {
                int col = wc * 32 + ni * 16 + (lane & 15);
                float val = (col <= row) ? qk[mi][ni][i] : 0.f;
                a_l[row][col] = f2bf(val);
                part += val;
            }
            part += __shfl_xor(part, 1);
            part += __shfl_xor(part, 2);
            part += __shfl_xor(part, 4);
            part += __shfl_xor(part, 8);
            if ((lane & 15) == 0) rsum[row][wc] = part;
        }
    {
        int row = t & 63, qq = t >> 6;
        float s = 0.f;
        #pragma unroll
        for (int m = 0; m < 32; ++m) s += bf2f(pq_l[row][qq * 32 + m]) * ksp_l[qq * 32 + m];
        rsum[row][4 + qq] = s;
    }
    __syncthreads();
    #pragma unroll
    for (int it = 0; it < 4; ++it) {
        int idx = t + it * 256;
        int r = idx >> 4, c8 = (idx & 15) << 3;
        *(bf16x8*)&pkst_l[r][c8] =
            *(const bf16x8*)(STbf + (((size_t)bh * NC_ + j) << 13) + r * 128 + c8);
    }
    if (t < 64) {
        float s = rsum[t][0] + rsum[t][1] + rsum[t][4] + rsum[t][5] + rsum[t][6] + rsum[t][7];
        den[t] = 1.0f / (s + 1e-6f);
    }
    __syncthreads();
    f32x4 oa[2][2];
    #pragma unroll
    for (int mi = 0; mi < 2; ++mi)
        #pragma unroll
        for (int ni = 0; ni < 2; ++ni) { f32x4 z = {0.f, 0.f, 0.f, 0.f}; oa[mi][ni] = z; }
    #pragma unroll
    for (int ks = 0; ks < 2; ++ks) {
        bf16x8 a0 = ld_frag(&a_l[0][0], wr * 32, ks * 32, 72);
        bf16x8 a1 = ld_frag(&a_l[0][0], wr * 32 + 16, ks * 32, 72);
        #pragma unroll
        for (int ni = 0; ni < 2; ++ni) {
            bf16x8 bb = ld_fragT(&v_l[0][0], wc * 32 + ni * 16, ks * 32, 72);
            oa[0][ni] = MFMA16(a0, bb, oa[0][ni]);
            oa[1][ni] = MFMA16(a1, bb, oa[1][ni]);
        }
    }
    #pragma unroll
    for (int ks = 0; ks < 4; ++ks) {
        bf16x8 a0 = ld_frag(&pq_l[0][0], wr * 32, ks * 32, 136);
        bf16x8 a1 = ld_frag(&pq_l[0][0], wr * 32 + 16, ks * 32, 136);
        #pragma unroll
        for (int ni = 0; ni < 2; ++ni) {
            bf16x8 bb = ld_frag(&pkst_l[0][0], wc * 32 + ni * 16, ks * 32, 136);
            oa[0][ni] = MFMA16(a0, bb, oa[0][ni]);
            oa[1][ni] = MFMA16(a1, bb, oa[1][ni]);
        }
    }
    const int b_ = bh >> 3, h = bh & 7;
    #pragma unroll
    for (int mi = 0; mi < 2; ++mi)
        #pragma unroll
        for (int ni = 0; ni < 2; ++ni)
            #pragma unroll
            for (int i = 0; i < 4; ++i) {
                int row = wr * 32 + mi * 16 + ((lane >> 4) << 2) + i;
                int col = wc * 32 + ni * 16 + (lane & 15);
                float val = oa[mi][ni][i] * den[row];
                size_t oi = ((size_t)b_ * N_ + n0 + row) * 512 + h * 64 + col;
                short hi = f2bf(val);
                o_hi[oi] = hi;
                o_lo[oi] = f2bf(val - bf2f(hi));
            }
}

// ---------------- output projection: out = o @ Wo^T + bo (hi/lo, global_load_lds) ----------------
__global__ __launch_bounds__(256) void gemm_out(
    const short* __restrict__ ohi, const short* __restrict__ olo,
    const short* __restrict__ Woh, const short* __restrict__ Wol,
    const float* __restrict__ bo, float* __restrict__ out)
{
    __shared__ short Ah[128 * 32];
    __shared__ short Al[128 * 32];
    __shared__ short Bh[128 * 32];
    __shared__ short Bl[128 * 32];
    const int t = threadIdx.x, lane = t & 63, wave = t >> 6;
    const int wr = wave >> 1, wc = wave & 1;
    const int row0 = blockIdx.x * 128, col0 = blockIdx.y * 128;
    const int l_row = lane >> 2, l_col = (lane & 3) << 3;
    f32x4 acc[4][4];
    #pragma unroll
    for (int m = 0; m < 4; ++m)
        #pragma unroll
        for (int n = 0; n < 4; ++n) { f32x4 z = {0.f, 0.f, 0.f, 0.f}; acc[m][n] = z; }
    for (int k0 = 0; k0 < 512; k0 += 32) {
        #pragma unroll
        for (int sub = 0; sub < 2; ++sub) {
            int s = wave * 2 + sub;
            int gr = s * 16 + l_row;
            size_t ga = (size_t)(row0 + gr) * 512 + k0 + l_col;
            size_t gb = (size_t)(col0 + gr) * 512 + k0 + l_col;
            gl16(&Ah[s * 512], ohi + ga);
            gl16(&Al[s * 512], olo + ga);
            gl16(&Bh[s * 512], Woh + gb);
            gl16(&Bl[s * 512], Wol + gb);
        }
        __syncthreads();
        bf16x8 bh[4], bl[4];
        #pragma unroll
        for (int n = 0; n < 4; ++n) {
            bh[n] = ld_frag(Bh, wc * 64 + n * 16, 0, 32);
            bl[n] = ld_frag(Bl, wc * 64 + n * 16, 0, 32);
        }
        #pragma unroll
        for (int m = 0; m < 4; ++m) {
            bf16x8 ah = ld_frag(Ah, wr * 64 + m * 16, 0, 32);
            bf16x8 al = ld_frag(Al, wr * 64 + m * 16, 0, 32);
            #pragma unroll
            for (int n = 0; n < 4; ++n) {
                acc[m][n] = MFMA16(al, bh[n], acc[m][n]);
                acc[m][n] = MFMA16(ah, bl[n], acc[m][n]);
                acc[m][n] = MFMA16(ah, bh[n], acc[m][n]);
            }
        }
        __syncthreads();
    }
    #pragma unroll
    for (int m = 0; m < 4; ++m)
        #pragma unroll
        for (int n = 0; n < 4; ++n)
            #pragma unroll
            for (int i = 0; i < 4; ++i) {
                int gr = row0 + wr * 64 + m * 16 + ((lane >> 4) << 2) + i;
                int gc = col0 + wc * 64 + n * 16 + (lane & 15);
                out[(size_t)gr * 512 + gc] = acc[m][n][i] + bo[gc];
            }
}

extern "C" void kernel_launch(void* const* d_in, const int* in_sizes, int n_in,
                              void* d_out, int out_size, void* d_ws, size_t ws_size,
                              hipStream_t stream) {
    const float* x     = (const float*)d_in[0];
    const float* omega = (const float*)d_in[1];
    const float* Wq    = (const float*)d_in[2];
    const float* Wk    = (const float*)d_in[3];
    const float* Wv    = (const float*)d_in[4];
    const float* Wo    = (const float*)d_in[5];
    const float* bo    = (const float*)d_in[6];
    float* out = (float*)d_out;

    char* w = (char*)d_ws;
    short* xh   = (short*)(w);                      // 0..4 MB   (later reused: phiq)
    short* xl   = (short*)(w + (4ull  << 20));      // 4..8      (phiq spans 0..8)
    short* Wch  = (short*)(w + (8ull  << 20));      // 8..11.5   (later reused: phik)
    short* Wcl  = (short*)(w + (11ull << 20) + (512ull << 10)); // 11.5..15
    short* Wohi = (short*)(w + (16ull << 20));      // 16..16.5
    short* Wolo = (short*)(w + (16ull << 20) + (512ull << 10)); // 16.5..17
    float* projq= (float*)(w + (17ull << 20));      // 17..33  (reused as S)
    float* projk= (float*)(w + (33ull << 20));      // 33..49  (reused as lp)
    short* vbf  = (short*)(w + (49ull << 20));      // 49..53
    short* STbf = (short*)(w + (53ull << 20));      // 53..61
    short* ohi  = (short*)(w + (61ull << 20));      // 61..65
    short* olo  = (short*)(w + (65ull << 20));      // 65..69
    float* ssqb = (float*)(w + (69ull << 20));                      // 256 KB
    float* ksum = (float*)(w + (69ull << 20) + (256ull << 10));     // 256 KB
    float* kpre = (float*)(w + (69ull << 20) + (512ull << 10));     // 256 KB
    float* pmax = (float*)(w + (69ull << 20) + (768ull << 10));     // 128 KB
    float* gmx  = (float*)(w + (69ull << 20) + (896ull << 10));     // 4 B
    short* phiq = (short*)(w);                      // over xh/xl (dead after gemm_fused)
    short* phik = (short*)(w + (8ull << 20));       // over Wch/Wcl (dead after gemm_fused)
    float* S    = projq;                            // over projq (dead after phi_all)

    split_scale<<<dim3(2048, 1, 5), 256, 0, stream>>>(x, Wq, Wk, Wv, Wo,
                                                      xh, xl, Wch, Wcl, Wohi, Wolo);
    prep_omw<<<128, 256, 0, stream>>>(omega, Wq, Wk, Wch, Wcl);
    gemm_fused<<<dim3(32, 28), 256, 0, stream>>>(xh, xl, Wch, Wcl, projq, projk, vbf, ssqb);
    phi_all<<<8192, 256, 0, stream>>>(projq, projk, ssqb, phiq, pmax);
    gmax_kernel<<<1, 256, 0, stream>>>(pmax, gmx);
    phik_exp<<<4096, 256, 0, stream>>>(projk, gmx, phik);
    chunk_kv_mfma<<<512, 256, 0, stream>>>(phik, vbf, S, ksum);
    prefix_scan<<<dim3(16, 33), 256, 0, stream>>>(S, ksum, STbf, kpre);
    chunk_out_mfma<<<512, 256, 0, stream>>>(phiq, phik, vbf, STbf, kpre, ohi, olo);
    gemm_out<<<dim3(32, 4), 256, 0, stream>>>(ohi, olo, Wohi, Wolo, bo, out);
}